// Round 1
// baseline (5082.722 us; speedup 1.0000x reference)
//
#include <hip/hip_runtime.h>

typedef __bf16 bf16;
typedef __attribute__((ext_vector_type(8))) __bf16 bf16x8;
typedef __attribute__((ext_vector_type(4))) __bf16 bf16x4;
typedef __attribute__((ext_vector_type(4))) float f32x4;

#define HD 256
#define GEMM_ACC 1
#define GEMM_GELU 2

__device__ __forceinline__ float gelu_f(float x) {
  return 0.5f * x * (1.0f + erff(x * 0.70710678118654752440f));
}

// ---------------- GEMM: C[M,N] (+)= act(A[M,K] @ W[K,N] + bias) ----------------
// A: [M,Kd] bf16 row-major.  Wt: [N,Kd] bf16 (weights pre-transposed).  C: [M,N] bf16.
// 128x128 block tile, 4 waves, each wave 64x64 via 4x4 grid of 16x16x32 MFMA.
__global__ __launch_bounds__(256) void gemm_k(
    const bf16* __restrict__ A, const bf16* __restrict__ Wt,
    const float* __restrict__ bias, bf16* __restrict__ C,
    int M, int N, int Kd, int flags)
{
  __shared__ bf16 sA[128][40];   // 32 cols + 8 pad (80B pitch -> 2-way banks, free)
  __shared__ bf16 sB[128][40];
  const int t = threadIdx.x;
  const int m0 = blockIdx.x * 128, n0 = blockIdx.y * 128;
  const int lane = t & 63, wid = t >> 6;
  const int wr = wid >> 1, wc = wid & 1;
  const int lm = lane & 15, quad = lane >> 4;

  f32x4 acc[4][4];
#pragma unroll
  for (int i = 0; i < 4; i++)
#pragma unroll
    for (int j = 0; j < 4; j++)
#pragma unroll
      for (int r = 0; r < 4; r++) acc[i][j][r] = 0.f;

  for (int kb = 0; kb < Kd; kb += 32) {
#pragma unroll
    for (int c = 0; c < 2; c++) {
      int cc = t + c * 256;
      int row = cc >> 2, seg = cc & 3;
      int gr = m0 + row;
      bf16x8 va;
#pragma unroll
      for (int q = 0; q < 8; q++) va[q] = (bf16)0.f;
      if (gr < M) va = *(const bf16x8*)(A + (size_t)gr * Kd + kb + seg * 8);
      *(bf16x8*)(&sA[row][seg * 8]) = va;
      bf16x8 vb = *(const bf16x8*)(Wt + (size_t)(n0 + row) * Kd + kb + seg * 8);
      *(bf16x8*)(&sB[row][seg * 8]) = vb;
    }
    __syncthreads();
    bf16x8 af[4], bv[4];
#pragma unroll
    for (int i = 0; i < 4; i++) af[i] = *(const bf16x8*)(&sA[wr * 64 + i * 16 + lm][quad * 8]);
#pragma unroll
    for (int j = 0; j < 4; j++) bv[j] = *(const bf16x8*)(&sB[wc * 64 + j * 16 + lm][quad * 8]);
#pragma unroll
    for (int i = 0; i < 4; i++)
#pragma unroll
      for (int j = 0; j < 4; j++)
        acc[i][j] = __builtin_amdgcn_mfma_f32_16x16x32_bf16(af[i], bv[j], acc[i][j], 0, 0, 0);
    __syncthreads();
  }
  // epilogue: C/D layout col=lane&15, row=quad*4+reg (m89-verified)
#pragma unroll
  for (int i = 0; i < 4; i++) {
#pragma unroll
    for (int r = 0; r < 4; r++) {
      int gr = m0 + wr * 64 + i * 16 + quad * 4 + r;
      if (gr < M) {
#pragma unroll
        for (int j = 0; j < 4; j++) {
          int gc = n0 + wc * 64 + j * 16 + lm;
          size_t idx = (size_t)gr * N + gc;
          float v = acc[i][j][r] + bias[gc];
          if (flags & GEMM_ACC) v += (float)C[idx];
          if (flags & GEMM_GELU) v = gelu_f(v);
          C[idx] = (bf16)v;
        }
      }
    }
  }
}

// ---------------- segment sum via CSR: out[s] = sum_{c in list(s)} in[c] ----------------
__global__ __launch_bounds__(256) void segsum_k(
    const int* __restrict__ offs, const int* __restrict__ cols,
    const bf16* __restrict__ in, bf16* __restrict__ out, int nseg)
{
  int wid = threadIdx.x >> 6, lane = threadIdx.x & 63;
  int seg = blockIdx.x * 4 + wid;
  if (seg >= nseg) return;
  int b = offs[seg], e = offs[seg + 1];
  float a0 = 0.f, a1 = 0.f, a2 = 0.f, a3 = 0.f;
  for (int i = b; i < e; i++) {
    int c = cols[i];
    bf16x4 v = *(const bf16x4*)(in + (size_t)c * HD + lane * 4);
    a0 += (float)v.x; a1 += (float)v.y; a2 += (float)v.z; a3 += (float)v.w;
  }
  bf16x4 o = {(bf16)a0, (bf16)a1, (bf16)a2, (bf16)a3};
  *(bf16x4*)(out + (size_t)seg * HD + lane * 4) = o;
}

// ---------------- fused residual + (gelu) + LayerNorm ----------------
__global__ __launch_bounds__(256) void ln_k(
    const bf16* __restrict__ X, const bf16* __restrict__ A,
    const float* __restrict__ gam, const float* __restrict__ bet,
    bf16* __restrict__ outb, float* __restrict__ outf, int M, int apply_gelu)
{
  int wid = threadIdx.x >> 6, lane = threadIdx.x & 63;
  int row = blockIdx.x * 4 + wid;
  if (row >= M) return;
  size_t base = (size_t)row * HD + lane * 4;
  bf16x4 xv = *(const bf16x4*)(X + base);
  bf16x4 av = *(const bf16x4*)(A + base);
  float s0, s1, s2, s3;
  if (apply_gelu) {
    s0 = (float)xv.x + gelu_f((float)av.x);
    s1 = (float)xv.y + gelu_f((float)av.y);
    s2 = (float)xv.z + gelu_f((float)av.z);
    s3 = (float)xv.w + gelu_f((float)av.w);
  } else {
    s0 = (float)xv.x + (float)av.x;
    s1 = (float)xv.y + (float)av.y;
    s2 = (float)xv.z + (float)av.z;
    s3 = (float)xv.w + (float)av.w;
  }
  float sum = s0 + s1 + s2 + s3;
#pragma unroll
  for (int o = 32; o; o >>= 1) sum += __shfl_xor(sum, o, 64);
  float mean = sum * (1.0f / 256.0f);
  float d0 = s0 - mean, d1 = s1 - mean, d2 = s2 - mean, d3 = s3 - mean;
  float vs = d0 * d0 + d1 * d1 + d2 * d2 + d3 * d3;
#pragma unroll
  for (int o = 32; o; o >>= 1) vs += __shfl_xor(vs, o, 64);
  float rstd = rsqrtf(vs * (1.0f / 256.0f) + 1e-5f);
  float4 g = *(const float4*)(gam + lane * 4);
  float4 bb = *(const float4*)(bet + lane * 4);
  float y0 = d0 * rstd * g.x + bb.x;
  float y1 = d1 * rstd * g.y + bb.y;
  float y2 = d2 * rstd * g.z + bb.z;
  float y3 = d3 * rstd * g.w + bb.w;
  if (outb) {
    bf16x4 o = {(bf16)y0, (bf16)y1, (bf16)y2, (bf16)y3};
    *(bf16x4*)(outb + base) = o;
  }
  if (outf) {
    float4 o = {y0, y1, y2, y3};
    *(float4*)(outf + base) = o;
  }
}

// ---------------- lg_x init: out[e] = bf16(rel_embed[feat[e]]) ----------------
__global__ __launch_bounds__(256) void gather_rel_k(
    const int* __restrict__ feat, const float* __restrict__ rel,
    bf16* __restrict__ out, int NE)
{
  int wid = threadIdx.x >> 6, lane = threadIdx.x & 63;
  int e = blockIdx.x * 4 + wid;
  if (e >= NE) return;
  int f = feat[e];
  float4 v = *(const float4*)(rel + (size_t)f * HD + lane * 4);
  bf16x4 o = {(bf16)v.x, (bf16)v.y, (bf16)v.z, (bf16)v.w};
  *(bf16x4*)(out + (size_t)e * HD + lane * 4) = o;
}

// ---------------- fused_edges: out[e] = x[src[e]] + x[dst[e]] ----------------
__global__ __launch_bounds__(256) void gather2_k(
    const int* __restrict__ src, const int* __restrict__ dst,
    const bf16* __restrict__ x, bf16* __restrict__ out, int NE)
{
  int wid = threadIdx.x >> 6, lane = threadIdx.x & 63;
  int e = blockIdx.x * 4 + wid;
  if (e >= NE) return;
  int s = src[e], d = dst[e];
  bf16x4 a = *(const bf16x4*)(x + (size_t)s * HD + lane * 4);
  bf16x4 b = *(const bf16x4*)(x + (size_t)d * HD + lane * 4);
  bf16x4 o = {(bf16)((float)a.x + (float)b.x), (bf16)((float)a.y + (float)b.y),
              (bf16)((float)a.z + (float)b.z), (bf16)((float)a.w + (float)b.w)};
  *(bf16x4*)(out + (size_t)e * HD + lane * 4) = o;
}

// ---------------- f32 -> bf16 ----------------
__global__ __launch_bounds__(256) void f2b_k(const float* __restrict__ in, bf16* __restrict__ out, int n4) {
  int i = blockIdx.x * 256 + threadIdx.x;
  if (i >= n4) return;
  float4 v = *(const float4*)(in + (size_t)i * 4);
  bf16x4 o = {(bf16)v.x, (bf16)v.y, (bf16)v.z, (bf16)v.w};
  *(bf16x4*)(out + (size_t)i * 4) = o;
}

// ---------------- weight transpose+convert: in [Kd][Nd] f32 -> out [Nd][Kd] bf16 ----------------
// blockIdx.y = matrix index (batched)
__global__ __launch_bounds__(256) void wtrans_k(const float* __restrict__ in, bf16* __restrict__ out,
                                                int Kd, int Nd) {
  size_t moff = (size_t)blockIdx.y * Kd * Nd;
  int id = blockIdx.x * 256 + threadIdx.x;
  if (id >= Kd * Nd) return;
  int n = id / Kd, k = id - n * Kd;
  out[moff + id] = (bf16)in[moff + (size_t)k * Nd + n];
}

// ---------------- CSR build ----------------
__global__ __launch_bounds__(256) void count_k(const int* __restrict__ keys, int n, int* __restrict__ cnt) {
  int i = blockIdx.x * 256 + threadIdx.x;
  if (i < n) atomicAdd(&cnt[keys[i]], 1);
}
__global__ __launch_bounds__(256) void scan1_k(const int* __restrict__ in, int* __restrict__ out,
                                               int* __restrict__ bsum, int n) {
  __shared__ int sh[256];
  int t = threadIdx.x;
  int i0 = blockIdx.x * 1024 + t * 4;
  int v0 = (i0 < n) ? in[i0] : 0;
  int v1 = (i0 + 1 < n) ? in[i0 + 1] : 0;
  int v2 = (i0 + 2 < n) ? in[i0 + 2] : 0;
  int v3 = (i0 + 3 < n) ? in[i0 + 3] : 0;
  int tsum = v0 + v1 + v2 + v3;
  sh[t] = tsum;
  __syncthreads();
  for (int o = 1; o < 256; o <<= 1) {
    int x = (t >= o) ? sh[t - o] : 0;
    __syncthreads();
    sh[t] += x;
    __syncthreads();
  }
  int e0 = sh[t] - tsum;  // exclusive prefix
  if (t == 255) bsum[blockIdx.x] = sh[255];
  if (i0 < n) out[i0] = e0;
  e0 += v0;
  if (i0 + 1 < n) out[i0 + 1] = e0;
  e0 += v1;
  if (i0 + 2 < n) out[i0 + 2] = e0;
  e0 += v2;
  if (i0 + 3 < n) out[i0 + 3] = e0;
}
__global__ void scan2_k(int* bsum, int nb, int* total) {
  if (threadIdx.x == 0 && blockIdx.x == 0) {
    int acc = 0;
    for (int i = 0; i < nb; i++) { int v = bsum[i]; bsum[i] = acc; acc += v; }
    *total = acc;
  }
}
__global__ __launch_bounds__(256) void scan3_k(int* out, const int* bsum, int n) {
  int i = blockIdx.x * 256 + threadIdx.x;
  if (i < n) out[i] += bsum[i >> 10];
}
__global__ __launch_bounds__(256) void fill_k(const int* __restrict__ keys, const int* __restrict__ vals,
                                              int n, int modE, int* __restrict__ cursor, int* __restrict__ cols) {
  int i = blockIdx.x * 256 + threadIdx.x;
  if (i >= n) return;
  int pos = atomicAdd(&cursor[keys[i]], 1);
  cols[pos] = vals ? vals[i] : (i < modE ? i : i - modE);
}

extern "C" void kernel_launch(void* const* d_in, const int* in_sizes, int n_in,
                              void* d_out, int out_size, void* d_ws, size_t ws_size,
                              hipStream_t stream)
{
  const float* x_in      = (const float*)d_in[0];
  const int*   edge_feat = (const int*)d_in[1];
  const int*   eig       = (const int*)d_in[2];   // [2, NE]: src row then dst row
  const int*   eil       = (const int*)d_in[3];   // [2, NL]
  const float* rel       = (const float*)d_in[4];
  const float* w_self = (const float*)d_in[5];
  const float* b_self = (const float*)d_in[6];
  const float* w_khop = (const float*)d_in[7];
  const float* b_khop = (const float*)d_in[8];
  const float* w_fuse = (const float*)d_in[9];
  const float* b_fuse = (const float*)d_in[10];
  const float* w_ff1  = (const float*)d_in[11];
  const float* b_ff1  = (const float*)d_in[12];
  const float* w_ff2  = (const float*)d_in[13];
  const float* b_ff2  = (const float*)d_in[14];
  const float* ln1_g  = (const float*)d_in[15];
  const float* ln1_b  = (const float*)d_in[16];
  const float* ln2_g  = (const float*)d_in[17];
  const float* ln2_b  = (const float*)d_in[18];

  const int NN = in_sizes[0] / HD;              // 20000
  const int NE = in_sizes[1];                   // 160000
  const int NL = in_sizes[3] / 2;               // 640000
  const int L  = in_sizes[5] / (2 * HD * HD);   // 2
  const int KH = in_sizes[7] / (L * 2 * HD * HD); // 4

  char* p = (char*)d_ws;
  auto alloc = [&](size_t bytes) -> void* {
    void* r = (void*)p;
    p += (bytes + 255) & ~(size_t)255;
    return r;
  };

  bf16* x_buf   = (bf16*)alloc((size_t)NN * HD * 2);
  bf16* fused_n = (bf16*)alloc((size_t)NN * HD * 2);   // doubles as t_n after LN1
  bf16* acc_n   = (bf16*)alloc((size_t)NN * HD * 2);
  bf16* z_na    = (bf16*)alloc((size_t)NN * HD * 2);
  bf16* z_nb    = (bf16*)alloc((size_t)NN * HD * 2);
  bf16* lg_buf  = (bf16*)alloc((size_t)NE * HD * 2);
  bf16* fused_e = (bf16*)alloc((size_t)NE * HD * 2);   // doubles as t_e after LN1
  bf16* acc_e   = (bf16*)alloc((size_t)NE * HD * 2);
  bf16* z_ea    = (bf16*)alloc((size_t)NE * HD * 2 * 2); // z_ea|z_eb contiguous; aliases ffn hidden buf
  bf16* z_eb    = z_ea + (size_t)NE * HD;
  bf16* hbuf    = z_ea;
  const int CH  = NE / 2;  // ffn row-chunk so hbuf (CH x 4H bf16) == z_ea+z_eb bytes exactly

  bf16* wself_t = (bf16*)alloc((size_t)L * 2 * HD * HD * 2);
  bf16* wkhop_t = (bf16*)alloc((size_t)L * 2 * KH * HD * HD * 2);
  bf16* wfuse_t = (bf16*)alloc((size_t)L * 2 * HD * HD * 2);
  bf16* wff1_t  = (bf16*)alloc((size_t)L * 2 * HD * 4 * HD * 2);
  bf16* wff2_t  = (bf16*)alloc((size_t)L * 2 * HD * 4 * HD * 2);

  int* inc_offs = (int*)alloc((size_t)(NN + 1) * 4);
  int* inc_cur  = (int*)alloc((size_t)NN * 4);
  int* inc_cols = (int*)alloc((size_t)2 * NE * 4);
  int* ng_offs  = (int*)alloc((size_t)(NN + 1) * 4);
  int* ng_cur   = (int*)alloc((size_t)NN * 4);
  int* ng_cols  = (int*)alloc((size_t)NE * 4);
  int* lg_offs  = (int*)alloc((size_t)(NE + 1) * 4);
  int* lg_cur   = (int*)alloc((size_t)NE * 4);
  int* lg_cols  = (int*)alloc((size_t)NL * 4);
  int* bsum     = (int*)alloc(3 * 256 * 4);

  // ---- weights: transpose + convert to bf16 [N][K] ----
  wtrans_k<<<dim3((HD * HD + 255) / 256, L * 2), 256, 0, stream>>>(w_self, wself_t, HD, HD);
  wtrans_k<<<dim3((HD * HD + 255) / 256, L * 2 * KH), 256, 0, stream>>>(w_khop, wkhop_t, HD, HD);
  wtrans_k<<<dim3((HD * HD + 255) / 256, L * 2), 256, 0, stream>>>(w_fuse, wfuse_t, HD, HD);
  wtrans_k<<<dim3((HD * 4 * HD + 255) / 256, L * 2), 256, 0, stream>>>(w_ff1, wff1_t, HD, 4 * HD);
  wtrans_k<<<dim3((HD * 4 * HD + 255) / 256, L * 2), 256, 0, stream>>>(w_ff2, wff2_t, 4 * HD, HD);

  // ---- activation init ----
  f2b_k<<<((NN * HD / 4) + 255) / 256, 256, 0, stream>>>(x_in, x_buf, NN * HD / 4);
  gather_rel_k<<<(NE + 3) / 4, 256, 0, stream>>>(edge_feat, rel, lg_buf, NE);

  // ---- CSR builds (graph is static across layers; rebuilt every launch) ----
  auto build_csr = [&](const int* keys, int nkeys, const int* vals, int modE,
                       int nseg, int* offs, int* cur, int* cols, int* bs) {
    int nb = (nseg + 1023) / 1024;
    hipMemsetAsync(offs, 0, (size_t)(nseg + 1) * 4, stream);
    count_k<<<(nkeys + 255) / 256, 256, 0, stream>>>(keys, nkeys, offs);
    scan1_k<<<nb, 256, 0, stream>>>(offs, offs, bs, nseg);
    scan2_k<<<1, 1, 0, stream>>>(bs, nb, offs + nseg);
    scan3_k<<<(nseg + 255) / 256, 256, 0, stream>>>(offs, bs, nseg);
    hipMemcpyAsync(cur, offs, (size_t)nseg * 4, hipMemcpyDeviceToDevice, stream);
    fill_k<<<(nkeys + 255) / 256, 256, 0, stream>>>(keys, vals, nkeys, modE, cur, cols);
  };
  build_csr(eig, 2 * NE, nullptr, NE, NN, inc_offs, inc_cur, inc_cols, bsum);        // incidence (both endpoints -> eid)
  build_csr(eig + NE, NE, eig, 0, NN, ng_offs, ng_cur, ng_cols, bsum + 256);          // key=dst_g, val=src_g
  build_csr(eil + NL, NL, eil, 0, NE, lg_offs, lg_cur, lg_cols, bsum + 512);          // key=dst_l, val=src_l

  float* out_x  = (float*)d_out;
  float* out_lg = (float*)d_out + (size_t)NN * HD;

  auto run_core = [&](bf16* xb, bf16* fus, bf16* accb, bf16* za, bf16* zb,
                      const int* coffs, const int* ccols, int M, int l, int c, float* outf) {
    size_t mi = (size_t)(l * 2 + c);
    dim3 g2((M + 127) / 128, 2);
    // prev = x @ ws + bs
    gemm_k<<<g2, 256, 0, stream>>>(xb, wself_t + mi * HD * HD, b_self + mi * HD, accb, M, HD, HD, 0);
    // k-hop: z=x; z=segsum(z); acc += z @ wk[i] + bk[i]
    const bf16* zin = xb;
    for (int i = 0; i < KH; i++) {
      bf16* zout = (i & 1) ? zb : za;
      segsum_k<<<(M + 3) / 4, 256, 0, stream>>>(coffs, ccols, zin, zout, M);
      gemm_k<<<g2, 256, 0, stream>>>(zout, wkhop_t + (mi * KH + i) * HD * HD,
                                     b_khop + (mi * KH + i) * HD, accb, M, HD, HD, GEMM_ACC);
      zin = zout;
    }
    // acc += fused @ wf + bf
    gemm_k<<<g2, 256, 0, stream>>>(fus, wfuse_t + mi * HD * HD, b_fuse + mi * HD, accb, M, HD, HD, GEMM_ACC);
    // t = LN1(x + gelu(acc))   (t overwrites fused buffer)
    ln_k<<<(M + 3) / 4, 256, 0, stream>>>(xb, accb, ln1_g + mi * HD, ln1_b + mi * HD,
                                          fus, (float*)nullptr, M, 1);
    // ffn (chunked so hidden fits hbuf): acc = gelu(t@w1+b1)@w2+b2
    for (int c0 = 0; c0 < M; c0 += CH) {
      int mc = (M - c0 < CH) ? (M - c0) : CH;
      gemm_k<<<dim3((mc + 127) / 128, 8), 256, 0, stream>>>(fus + (size_t)c0 * HD, wff1_t + mi * HD * 4 * HD,
                                                            b_ff1 + mi * 4 * HD, hbuf, mc, 4 * HD, HD, GEMM_GELU);
      gemm_k<<<dim3((mc + 127) / 128, 2), 256, 0, stream>>>(hbuf, wff2_t + mi * HD * 4 * HD,
                                                            b_ff2 + mi * HD, accb + (size_t)c0 * HD, mc, HD, 4 * HD, 0);
    }
    // x_new = LN2(t + acc) -> xb (and f32 d_out on last layer)
    ln_k<<<(M + 3) / 4, 256, 0, stream>>>(fus, accb, ln2_g + mi * HD, ln2_b + mi * HD, xb, outf, M, 0);
  };

  for (int l = 0; l < L; l++) {
    // fused_nodes = segsum(lg_x by src_g) + segsum(lg_x by dst_g)  (incidence CSR)
    segsum_k<<<(NN + 3) / 4, 256, 0, stream>>>(inc_offs, inc_cols, lg_buf, fused_n, NN);
    // fused_edges = x[src_g] + x[dst_g]
    gather2_k<<<(NE + 3) / 4, 256, 0, stream>>>(eig, eig + NE, x_buf, fused_e, NE);
    run_core(x_buf, fused_n, acc_n, z_na, z_nb, ng_offs, ng_cols, NN, l, 0,
             (l == L - 1) ? out_x : nullptr);
    run_core(lg_buf, fused_e, acc_e, z_ea, z_eb, lg_offs, lg_cols, NE, l, 1,
             (l == L - 1) ? out_lg : nullptr);
  }
}

// Round 2
// 3623.541 us; speedup vs baseline: 1.4027x; 1.4027x over previous
//
#include <hip/hip_runtime.h>

typedef __bf16 bf16;
typedef __attribute__((ext_vector_type(8))) __bf16 bf16x8;
typedef __attribute__((ext_vector_type(4))) __bf16 bf16x4;
typedef __attribute__((ext_vector_type(4))) float f32x4;

#define HD 256
#define GEMM_GELU 2

__device__ __forceinline__ float gelu_f(float x) {
  return 0.5f * x * (1.0f + erff(x * 0.70710678118654752440f));
}

__device__ __forceinline__ void gload_lds16(const void* g, void* l) {
  __builtin_amdgcn_global_load_lds(
      (const __attribute__((address_space(1))) unsigned int*)g,
      (__attribute__((address_space(3))) unsigned int*)l, 16, 0, 0);
}

// ---------------- GEMM: C[M,N] = act(A[M,K] @ W[K,N] + bias) ----------------
// A: [M,*] bf16 row-stride lda.  Wt: [N,Kd] bf16 (pre-transposed, contiguous).
// C: [M,*] bf16 row-stride ldc.  N = gridDim.x*128 (always multiple of 128).
// grid = (nblocks, mblocks): n-fastest dispatch order -> A-tile reuse in L2/LLC.
// 128x128 tile, 4 waves, 4x4 of 16x16x32 MFMA per wave; global_load_lds staging.
__global__ __launch_bounds__(256) void gemm_k(
    const bf16* __restrict__ A, const bf16* __restrict__ Wt,
    const float* __restrict__ bias, bf16* __restrict__ C,
    int M, int Kd, int lda, int ldc, int flags)
{
  __shared__ __align__(16) bf16 sA[128 * 32];   // unpadded: required by global_load_lds
  __shared__ __align__(16) bf16 sB[128 * 32];
  const int t = threadIdx.x;
  const int lane = t & 63, w = t >> 6;
  const int n0 = blockIdx.x * 128, m0 = blockIdx.y * 128;
  const int wr = w >> 1, wc = w & 1;
  const int lm = lane & 15, quad = lane >> 4;

  // staging geometry: thread t stages 16B at tile byte offset r*4096 + t*16
  const int srow = t >> 2;              // row within tile (round 0)
  const int scolb = (t & 3) * 16;       // byte offset within 64B k-chunk of a row
  const bool full = (m0 + 128 <= M);

  const char* a0 = (const char*)(A + (size_t)(m0 + srow) * lda) + scolb;
  const char* a1 = (const char*)(A + (size_t)(m0 + srow + 64) * lda) + scolb;
  const char* b0 = (const char*)(Wt + (size_t)(n0 + srow) * Kd) + scolb;
  const char* b1 = (const char*)(Wt + (size_t)(n0 + srow + 64) * Kd) + scolb;
  bf16* lA0 = sA + w * 512;             // wave-uniform LDS bases (elements)
  bf16* lA1 = sA + 2048 + w * 512;
  bf16* lB0 = sB + w * 512;
  bf16* lB1 = sB + 2048 + w * 512;

  f32x4 acc[4][4];
#pragma unroll
  for (int i = 0; i < 4; i++)
#pragma unroll
    for (int j = 0; j < 4; j++)
#pragma unroll
      for (int r = 0; r < 4; r++) acc[i][j][r] = 0.f;

  for (int kb = 0; kb < Kd; kb += 32) {
    size_t ko = (size_t)kb * 2;
    if (full) {
      gload_lds16(a0 + ko, lA0);
      gload_lds16(a1 + ko, lA1);
    } else {
#pragma unroll
      for (int c = 0; c < 2; c++) {
        int row = srow + c * 64;
        int gr = m0 + row;
        bf16x8 va;
#pragma unroll
        for (int q = 0; q < 8; q++) va[q] = (bf16)0.f;
        if (gr < M) va = *(const bf16x8*)((const char*)(A + (size_t)gr * lda) + ko + scolb);
        *(bf16x8*)(sA + row * 32 + (scolb >> 1)) = va;
      }
    }
    gload_lds16(b0 + ko, lB0);
    gload_lds16(b1 + ko, lB1);
    __syncthreads();
    bf16x8 af[4], bv[4];
#pragma unroll
    for (int i = 0; i < 4; i++) af[i] = *(const bf16x8*)(sA + (wr * 64 + i * 16 + lm) * 32 + quad * 8);
#pragma unroll
    for (int j = 0; j < 4; j++) bv[j] = *(const bf16x8*)(sB + (wc * 64 + j * 16 + lm) * 32 + quad * 8);
#pragma unroll
    for (int i = 0; i < 4; i++)
#pragma unroll
      for (int j = 0; j < 4; j++)
        acc[i][j] = __builtin_amdgcn_mfma_f32_16x16x32_bf16(af[i], bv[j], acc[i][j], 0, 0, 0);
    __syncthreads();
  }
  // epilogue: C/D layout col=lane&15, row=quad*4+reg (m89-verified)
#pragma unroll
  for (int i = 0; i < 4; i++) {
#pragma unroll
    for (int r = 0; r < 4; r++) {
      int gr = m0 + wr * 64 + i * 16 + quad * 4 + r;
      if (gr < M) {
#pragma unroll
        for (int j = 0; j < 4; j++) {
          int gc = n0 + wc * 64 + j * 16 + lm;
          float v = acc[i][j][r] + bias[gc];
          if (flags & GEMM_GELU) v = gelu_f(v);
          C[(size_t)gr * ldc + gc] = (bf16)v;
        }
      }
    }
  }
}

// ---------------- segment sum via CSR (strided rows) ----------------
__global__ __launch_bounds__(256) void segsum_k(
    const int* __restrict__ offs, const int* __restrict__ cols,
    const bf16* __restrict__ in, int ldin, bf16* __restrict__ out, int ldout, int nseg)
{
  int wid = threadIdx.x >> 6, lane = threadIdx.x & 63;
  int seg = blockIdx.x * 4 + wid;
  if (seg >= nseg) return;
  int b = offs[seg], e = offs[seg + 1];
  float a0 = 0.f, a1 = 0.f, a2 = 0.f, a3 = 0.f;
  for (int i = b; i < e; i++) {
    int c = cols[i];
    bf16x4 v = *(const bf16x4*)(in + (size_t)c * ldin + lane * 4);
    a0 += (float)v.x; a1 += (float)v.y; a2 += (float)v.z; a3 += (float)v.w;
  }
  bf16x4 o = {(bf16)a0, (bf16)a1, (bf16)a2, (bf16)a3};
  *(bf16x4*)(out + (size_t)seg * ldout + lane * 4) = o;
}

// ---------------- fused residual + (gelu) + LayerNorm ----------------
// X/outb share row-stride ldx; A and outf are dense (stride 256).
__global__ __launch_bounds__(256) void ln_k(
    const bf16* __restrict__ X, int ldx, const bf16* __restrict__ A,
    const float* __restrict__ gam, const float* __restrict__ bet,
    bf16* __restrict__ outb, float* __restrict__ outf, int M, int apply_gelu)
{
  int wid = threadIdx.x >> 6, lane = threadIdx.x & 63;
  int row = blockIdx.x * 4 + wid;
  if (row >= M) return;
  size_t xbase = (size_t)row * ldx + lane * 4;
  size_t abase = (size_t)row * HD + lane * 4;
  bf16x4 xv = *(const bf16x4*)(X + xbase);
  bf16x4 av = *(const bf16x4*)(A + abase);
  float s0, s1, s2, s3;
  if (apply_gelu) {
    s0 = (float)xv.x + gelu_f((float)av.x);
    s1 = (float)xv.y + gelu_f((float)av.y);
    s2 = (float)xv.z + gelu_f((float)av.z);
    s3 = (float)xv.w + gelu_f((float)av.w);
  } else {
    s0 = (float)xv.x + (float)av.x;
    s1 = (float)xv.y + (float)av.y;
    s2 = (float)xv.z + (float)av.z;
    s3 = (float)xv.w + (float)av.w;
  }
  float sum = s0 + s1 + s2 + s3;
#pragma unroll
  for (int o = 32; o; o >>= 1) sum += __shfl_xor(sum, o, 64);
  float mean = sum * (1.0f / 256.0f);
  float d0 = s0 - mean, d1 = s1 - mean, d2 = s2 - mean, d3 = s3 - mean;
  float vs = d0 * d0 + d1 * d1 + d2 * d2 + d3 * d3;
#pragma unroll
  for (int o = 32; o; o >>= 1) vs += __shfl_xor(vs, o, 64);
  float rstd = rsqrtf(vs * (1.0f / 256.0f) + 1e-5f);
  float4 g = *(const float4*)(gam + lane * 4);
  float4 bb = *(const float4*)(bet + lane * 4);
  float y0 = d0 * rstd * g.x + bb.x;
  float y1 = d1 * rstd * g.y + bb.y;
  float y2 = d2 * rstd * g.z + bb.z;
  float y3 = d3 * rstd * g.w + bb.w;
  if (outb) {
    bf16x4 o = {(bf16)y0, (bf16)y1, (bf16)y2, (bf16)y3};
    *(bf16x4*)(outb + xbase) = o;
  }
  if (outf) {
    float4 o = {y0, y1, y2, y3};
    *(float4*)(outf + abase) = o;
  }
}

// ---------------- lg_x init: out[e] = bf16(rel_embed[feat[e]]) ----------------
__global__ __launch_bounds__(256) void gather_rel_k(
    const int* __restrict__ feat, const float* __restrict__ rel,
    bf16* __restrict__ out, int ldout, int NE)
{
  int wid = threadIdx.x >> 6, lane = threadIdx.x & 63;
  int e = blockIdx.x * 4 + wid;
  if (e >= NE) return;
  int f = feat[e];
  float4 v = *(const float4*)(rel + (size_t)f * HD + lane * 4);
  bf16x4 o = {(bf16)v.x, (bf16)v.y, (bf16)v.z, (bf16)v.w};
  *(bf16x4*)(out + (size_t)e * ldout + lane * 4) = o;
}

// ---------------- fused_edges: out[e] = x[src[e]] + x[dst[e]] ----------------
__global__ __launch_bounds__(256) void gather2_k(
    const int* __restrict__ src, const int* __restrict__ dst,
    const bf16* __restrict__ x, int ldx, bf16* __restrict__ out, int ldout, int NE)
{
  int wid = threadIdx.x >> 6, lane = threadIdx.x & 63;
  int e = blockIdx.x * 4 + wid;
  if (e >= NE) return;
  int s = src[e], d = dst[e];
  bf16x4 a = *(const bf16x4*)(x + (size_t)s * ldx + lane * 4);
  bf16x4 b = *(const bf16x4*)(x + (size_t)d * ldx + lane * 4);
  bf16x4 o = {(bf16)((float)a.x + (float)b.x), (bf16)((float)a.y + (float)b.y),
              (bf16)((float)a.z + (float)b.z), (bf16)((float)a.w + (float)b.w)};
  *(bf16x4*)(out + (size_t)e * ldout + lane * 4) = o;
}

// ---------------- f32 row copy -> bf16 strided ----------------
__global__ __launch_bounds__(256) void f2b_k(const float* __restrict__ in,
                                             bf16* __restrict__ out, int ldout, int M) {
  int wid = threadIdx.x >> 6, lane = threadIdx.x & 63;
  int row = blockIdx.x * 4 + wid;
  if (row >= M) return;
  float4 v = *(const float4*)(in + (size_t)row * HD + lane * 4);
  bf16x4 o = {(bf16)v.x, (bf16)v.y, (bf16)v.z, (bf16)v.w};
  *(bf16x4*)(out + (size_t)row * ldout + lane * 4) = o;
}

// ---------------- weight transpose+convert: in [Kd][Nd] f32 -> out [Nd][Kd] bf16 ----------------
__global__ __launch_bounds__(256) void wtrans_k(const float* __restrict__ in, bf16* __restrict__ out,
                                                int Kd, int Nd) {
  size_t moff = (size_t)blockIdx.y * Kd * Nd;
  int id = blockIdx.x * 256 + threadIdx.x;
  if (id >= Kd * Nd) return;
  int n = id / Kd, k = id - n * Kd;
  out[moff + id] = (bf16)in[moff + (size_t)k * Nd + n];
}

// ---------------- cat weight build: out[mi][n][s*256+k] = W_s[mi][k][n] ----------------
__global__ __launch_bounds__(256) void wcat_k(const float* __restrict__ ws, const float* __restrict__ wk,
                                              const float* __restrict__ wf, bf16* __restrict__ out,
                                              int KH, int CW) {
  int mi = blockIdx.y;
  int id = blockIdx.x * 256 + threadIdx.x;  // over HD*CW, id = n*CW + k
  if (id >= HD * CW) return;
  int n = id / CW, k = id - n * CW;
  int s = k >> 8, kk = k & 255;
  float v;
  if (s == 0)       v = ws[((size_t)mi * HD + kk) * HD + n];
  else if (s <= KH) v = wk[(((size_t)mi * KH + (s - 1)) * HD + kk) * HD + n];
  else              v = wf[((size_t)mi * HD + kk) * HD + n];
  out[(size_t)mi * HD * CW + id] = (bf16)v;
}

// ---------------- cat bias: bcat[mi][n] = b_self + sum b_khop + b_fuse ----------------
__global__ __launch_bounds__(256) void bcat_k(const float* __restrict__ bs, const float* __restrict__ bk,
                                              const float* __restrict__ bf, float* __restrict__ out, int KH) {
  int mi = blockIdx.x, n = threadIdx.x;
  float v = bs[(size_t)mi * HD + n] + bf[(size_t)mi * HD + n];
  for (int i = 0; i < KH; i++) v += bk[((size_t)mi * KH + i) * HD + n];
  out[(size_t)mi * HD + n] = v;
}

// ---------------- CSR build ----------------
__global__ __launch_bounds__(256) void count_k(const int* __restrict__ keys, int n, int* __restrict__ cnt) {
  int i = blockIdx.x * 256 + threadIdx.x;
  if (i < n) atomicAdd(&cnt[keys[i]], 1);
}
__global__ __launch_bounds__(256) void scan1_k(const int* __restrict__ in, int* __restrict__ out,
                                               int* __restrict__ bsum, int n) {
  __shared__ int sh[256];
  int t = threadIdx.x;
  int i0 = blockIdx.x * 1024 + t * 4;
  int v0 = (i0 < n) ? in[i0] : 0;
  int v1 = (i0 + 1 < n) ? in[i0 + 1] : 0;
  int v2 = (i0 + 2 < n) ? in[i0 + 2] : 0;
  int v3 = (i0 + 3 < n) ? in[i0 + 3] : 0;
  int tsum = v0 + v1 + v2 + v3;
  sh[t] = tsum;
  __syncthreads();
  for (int o = 1; o < 256; o <<= 1) {
    int x = (t >= o) ? sh[t - o] : 0;
    __syncthreads();
    sh[t] += x;
    __syncthreads();
  }
  int e0 = sh[t] - tsum;
  if (t == 255) bsum[blockIdx.x] = sh[255];
  if (i0 < n) out[i0] = e0;
  e0 += v0;
  if (i0 + 1 < n) out[i0 + 1] = e0;
  e0 += v1;
  if (i0 + 2 < n) out[i0 + 2] = e0;
  e0 += v2;
  if (i0 + 3 < n) out[i0 + 3] = e0;
}
__global__ void scan2_k(int* bsum, int nb, int* total) {
  if (threadIdx.x == 0 && blockIdx.x == 0) {
    int acc = 0;
    for (int i = 0; i < nb; i++) { int v = bsum[i]; bsum[i] = acc; acc += v; }
    *total = acc;
  }
}
__global__ __launch_bounds__(256) void scan3_k(int* out, const int* bsum, int n) {
  int i = blockIdx.x * 256 + threadIdx.x;
  if (i < n) out[i] += bsum[i >> 10];
}
__global__ __launch_bounds__(256) void fill_k(const int* __restrict__ keys, const int* __restrict__ vals,
                                              int n, int modE, int* __restrict__ cursor, int* __restrict__ cols) {
  int i = blockIdx.x * 256 + threadIdx.x;
  if (i >= n) return;
  int pos = atomicAdd(&cursor[keys[i]], 1);
  cols[pos] = vals ? vals[i] : (i < modE ? i : i - modE);
}

extern "C" void kernel_launch(void* const* d_in, const int* in_sizes, int n_in,
                              void* d_out, int out_size, void* d_ws, size_t ws_size,
                              hipStream_t stream)
{
  const float* x_in      = (const float*)d_in[0];
  const int*   edge_feat = (const int*)d_in[1];
  const int*   eig       = (const int*)d_in[2];
  const int*   eil       = (const int*)d_in[3];
  const float* rel       = (const float*)d_in[4];
  const float* w_self = (const float*)d_in[5];
  const float* b_self = (const float*)d_in[6];
  const float* w_khop = (const float*)d_in[7];
  const float* b_khop = (const float*)d_in[8];
  const float* w_fuse = (const float*)d_in[9];
  const float* b_fuse = (const float*)d_in[10];
  const float* w_ff1  = (const float*)d_in[11];
  const float* b_ff1  = (const float*)d_in[12];
  const float* w_ff2  = (const float*)d_in[13];
  const float* b_ff2  = (const float*)d_in[14];
  const float* ln1_g  = (const float*)d_in[15];
  const float* ln1_b  = (const float*)d_in[16];
  const float* ln2_g  = (const float*)d_in[17];
  const float* ln2_b  = (const float*)d_in[18];

  const int NN = in_sizes[0] / HD;
  const int NE = in_sizes[1];
  const int NL = in_sizes[3] / 2;
  const int L  = in_sizes[5] / (2 * HD * HD);
  const int KH = in_sizes[7] / (L * 2 * HD * HD);
  const int CW = (KH + 2) * HD;   // cat width: x | z1..zKH | fused

  char* p = (char*)d_ws;
  auto alloc = [&](size_t bytes) -> void* {
    void* r = (void*)p;
    p += (bytes + 255) & ~(size_t)255;
    return r;
  };

  bf16* n_cat  = (bf16*)alloc((size_t)NN * CW * 2);
  bf16* lg_cat = (bf16*)alloc((size_t)NE * CW * 2);
  bf16* acc_n  = (bf16*)alloc((size_t)NN * HD * 2);
  bf16* acc_e  = (bf16*)alloc((size_t)NE * HD * 2);

  bf16*  wcat_t = (bf16*)alloc((size_t)L * 2 * HD * CW * 2);
  float* bcat   = (float*)alloc((size_t)L * 2 * HD * 4);
  bf16*  wff1_t = (bf16*)alloc((size_t)L * 2 * HD * 4 * HD * 2);
  bf16*  wff2_t = (bf16*)alloc((size_t)L * 2 * HD * 4 * HD * 2);

  int* inc_offs = (int*)alloc((size_t)(NN + 1) * 4);
  int* inc_cur  = (int*)alloc((size_t)NN * 4);
  int* inc_cols = (int*)alloc((size_t)2 * NE * 4);
  int* ng_offs  = (int*)alloc((size_t)(NN + 1) * 4);
  int* ng_cur   = (int*)alloc((size_t)NN * 4);
  int* ng_cols  = (int*)alloc((size_t)NE * 4);
  int* lg_offs  = (int*)alloc((size_t)(NE + 1) * 4);
  int* lg_cur   = (int*)alloc((size_t)NE * 4);
  int* lg_cols  = (int*)alloc((size_t)NL * 4);
  int* bsum     = (int*)alloc(3 * 256 * 4);

  // ---- weights ----
  wcat_k<<<dim3((HD * CW + 255) / 256, L * 2), 256, 0, stream>>>(w_self, w_khop, w_fuse, wcat_t, KH, CW);
  bcat_k<<<L * 2, 256, 0, stream>>>(b_self, b_khop, b_fuse, bcat, KH);
  wtrans_k<<<dim3((HD * 4 * HD + 255) / 256, L * 2), 256, 0, stream>>>(w_ff1, wff1_t, HD, 4 * HD);
  wtrans_k<<<dim3((HD * 4 * HD + 255) / 256, L * 2), 256, 0, stream>>>(w_ff2, wff2_t, 4 * HD, HD);

  // ---- activation init ----
  f2b_k<<<(NN + 3) / 4, 256, 0, stream>>>(x_in, n_cat, CW, NN);
  gather_rel_k<<<(NE + 3) / 4, 256, 0, stream>>>(edge_feat, rel, lg_cat, CW, NE);

  // ---- CSR builds ----
  auto build_csr = [&](const int* keys, int nkeys, const int* vals, int modE,
                       int nseg, int* offs, int* cur, int* cols, int* bs) {
    int nb = (nseg + 1023) / 1024;
    hipMemsetAsync(offs, 0, (size_t)(nseg + 1) * 4, stream);
    count_k<<<(nkeys + 255) / 256, 256, 0, stream>>>(keys, nkeys, offs);
    scan1_k<<<nb, 256, 0, stream>>>(offs, offs, bs, nseg);
    scan2_k<<<1, 1, 0, stream>>>(bs, nb, offs + nseg);
    scan3_k<<<(nseg + 255) / 256, 256, 0, stream>>>(offs, bs, nseg);
    hipMemcpyAsync(cur, offs, (size_t)nseg * 4, hipMemcpyDeviceToDevice, stream);
    fill_k<<<(nkeys + 255) / 256, 256, 0, stream>>>(keys, vals, nkeys, modE, cur, cols);
  };
  build_csr(eig, 2 * NE, nullptr, NE, NN, inc_offs, inc_cur, inc_cols, bsum);
  build_csr(eig + NE, NE, eig, 0, NN, ng_offs, ng_cur, ng_cols, bsum + 256);
  build_csr(eil + NL, NL, eil, 0, NE, lg_offs, lg_cur, lg_cols, bsum + 512);

  float* out_x  = (float*)d_out;
  float* out_lg = (float*)d_out + (size_t)NN * HD;

  auto run_core = [&](bf16* cat, bf16* accb, const int* coffs, const int* ccols,
                      int M, int l, int c, float* outf) {
    size_t mi = (size_t)(l * 2 + c);
    int mb = (M + 127) / 128;
    // khop chain into slices 1..KH (reads slice i-1, writes slice i)
    for (int i = 1; i <= KH; i++)
      segsum_k<<<(M + 3) / 4, 256, 0, stream>>>(coffs, ccols, cat + (size_t)(i - 1) * HD, CW,
                                                cat + (size_t)i * HD, CW, M);
    // acc = cat @ Wcat + bcat   (self + khops + fuse, one K=1536 GEMM)
    gemm_k<<<dim3(2, mb), 256, 0, stream>>>(cat, wcat_t + mi * HD * CW, bcat + mi * HD,
                                            accb, M, CW, CW, HD, 0);
    // t = LN1(x + gelu(acc)) -> slice0 (overwrites x; x no longer needed)
    ln_k<<<(M + 3) / 4, 256, 0, stream>>>(cat, CW, accb, ln1_g + mi * HD, ln1_b + mi * HD,
                                          cat, (float*)nullptr, M, 1);
    // hidden (slices 1..4, cols 256..1279) = gelu(t @ w1 + b1)
    gemm_k<<<dim3(8, mb), 256, 0, stream>>>(cat, wff1_t + mi * HD * 4 * HD, b_ff1 + mi * 4 * HD,
                                            cat + HD, M, HD, CW, CW, GEMM_GELU);
    // acc = hidden @ w2 + b2
    gemm_k<<<dim3(2, mb), 256, 0, stream>>>(cat + HD, wff2_t + mi * 4 * HD * HD, b_ff2 + mi * HD,
                                            accb, M, 4 * HD, CW, HD, 0);
    // x_new = LN2(t + acc) -> slice0 (+ f32 out on last layer)
    ln_k<<<(M + 3) / 4, 256, 0, stream>>>(cat, CW, accb, ln2_g + mi * HD, ln2_b + mi * HD,
                                          cat, outf, M, 0);
  };

  for (int l = 0; l < L; l++) {
    // fused_nodes = segsum over incidence of lg_x (slice0 of lg_cat) -> node slice KH+1
    segsum_k<<<(NN + 3) / 4, 256, 0, stream>>>(inc_offs, inc_cols, lg_cat, CW,
                                               n_cat + (size_t)(KH + 1) * HD, CW, NN);
    // fused_edges = x[src] + x[dst] -> lg slice KH+1
    gather2_k<<<(NE + 3) / 4, 256, 0, stream>>>(eig, eig + NE, n_cat, CW,
                                                lg_cat + (size_t)(KH + 1) * HD, CW, NE);
    run_core(n_cat, acc_n, ng_offs, ng_cols, NN, l, 0, (l == L - 1) ? out_x : nullptr);
    run_core(lg_cat, acc_e, lg_offs, lg_cols, NE, l, 1, (l == L - 1) ? out_lg : nullptr);
  }
}

// Round 3
// 3332.220 us; speedup vs baseline: 1.5253x; 1.0874x over previous
//
#include <hip/hip_runtime.h>

typedef __bf16 bf16;
typedef __attribute__((ext_vector_type(8))) __bf16 bf16x8;
typedef __attribute__((ext_vector_type(4))) __bf16 bf16x4;
typedef __attribute__((ext_vector_type(4))) float f32x4;

#define HD 256
#define GEMM_GELU 2

// fast gelu: tanh form via hardware exp. |err vs exact erf-gelu| <= ~0.004,
// well inside the bf16 tolerance; ~8 VALU ops vs ~30 for erff.
__device__ __forceinline__ float gelu_f(float x) {
  float x2 = x * x;
  float u = 1.5957691216057308f * x * fmaf(0.044715f, x2, 1.0f);
  float e = __expf(-u);               // v_exp_f32
  return x / (1.0f + e);              // x * sigmoid(u)
}

__device__ __forceinline__ void gload_lds16(const void* g, void* l) {
  __builtin_amdgcn_global_load_lds(
      (const __attribute__((address_space(1))) unsigned int*)g,
      (__attribute__((address_space(3))) unsigned int*)l, 16, 0, 0);
}

// ---------------- GEMM: C[M,N] = act(A[M,K] @ W[K,N] + bias) ----------------
// A: [M,*] bf16 row-stride lda.  Wt: [N,Kd] bf16 (pre-transposed, contiguous).
// C: [M,*] bf16 row-stride ldc.  N = gridDim.x*128 (multiple of 128).
// 128x128 tile, 4 waves, 4x4 of 16x16x32 MFMA (operands swapped: Wt frag is the
// A-operand so D gives 4 consecutive n-cols per thread -> bf16x4 stores).
// LDS staging via global_load_lds w/ xor k-chunk swizzle (bank-conflict-free).
__global__ __launch_bounds__(256) void gemm_k(
    const bf16* __restrict__ A, const bf16* __restrict__ Wt,
    const float* __restrict__ bias, bf16* __restrict__ C,
    int M, int Kd, int lda, int ldc, int flags)
{
  __shared__ __align__(16) bf16 sA[128 * 32];   // unpadded (global_load_lds)
  __shared__ __align__(16) bf16 sB[128 * 32];
  const int t = threadIdx.x;
  const int lane = t & 63, w = t >> 6;
  const int n0 = blockIdx.x * 128, m0 = blockIdx.y * 128;
  const int wr = w >> 1, wc = w & 1;
  const int lm = lane & 15, quad = lane >> 4;

  // staging: thread t owns LDS slot (row=t>>2, chunk=t&3) of 16B; the data
  // placed there is global k-chunk cg = (t&3) ^ ((t>>3)&3)  [xor swizzle]
  const int srow = t >> 2;
  const int cg = (t & 3) ^ ((t >> 3) & 3);
  const bool full = (m0 + 128 <= M);

  const char* a0 = (const char*)(A + (size_t)(m0 + srow) * lda) + cg * 16;
  const char* a1 = (const char*)(A + (size_t)(m0 + srow + 64) * lda) + cg * 16;
  const char* b0 = (const char*)(Wt + (size_t)(n0 + srow) * Kd) + cg * 16;
  const char* b1 = (const char*)(Wt + (size_t)(n0 + srow + 64) * Kd) + cg * 16;
  bf16* lA0 = sA + w * 512;             // wave-uniform LDS bases
  bf16* lA1 = sA + 2048 + w * 512;
  bf16* lB0 = sB + w * 512;
  bf16* lB1 = sB + 2048 + w * 512;

  // fragment read offset: chunk quad of row lm sits at slot quad ^ ((lm>>1)&3)
  const int soff = (quad ^ ((lm >> 1) & 3)) * 8;   // elements

  f32x4 acc[4][4];
#pragma unroll
  for (int i = 0; i < 4; i++)
#pragma unroll
    for (int j = 0; j < 4; j++)
#pragma unroll
      for (int r = 0; r < 4; r++) acc[i][j][r] = 0.f;

  for (int kb = 0; kb < Kd; kb += 32) {
    size_t ko = (size_t)kb * 2;
    if (full) {
      gload_lds16(a0 + ko, lA0);
      gload_lds16(a1 + ko, lA1);
    } else {
#pragma unroll
      for (int c = 0; c < 2; c++) {
        int row = srow + c * 64;
        int gr = m0 + row;
        bf16x8 va;
#pragma unroll
        for (int q = 0; q < 8; q++) va[q] = (bf16)0.f;
        if (gr < M) va = *(const bf16x8*)((const char*)(A + (size_t)gr * lda) + ko + cg * 16);
        *(bf16x8*)(sA + row * 32 + (t & 3) * 8) = va;
      }
    }
    gload_lds16(b0 + ko, lB0);
    gload_lds16(b1 + ko, lB1);
    __syncthreads();
    bf16x8 af[4], bv[4];
#pragma unroll
    for (int i = 0; i < 4; i++) af[i] = *(const bf16x8*)(sA + (wr * 64 + i * 16 + lm) * 32 + soff);
#pragma unroll
    for (int j = 0; j < 4; j++) bv[j] = *(const bf16x8*)(sB + (wc * 64 + j * 16 + lm) * 32 + soff);
    // swapped operands: D[n][m] layout -> acc[i][j] row index = n (quad*4+r), col = m (lm)
#pragma unroll
    for (int i = 0; i < 4; i++)
#pragma unroll
      for (int j = 0; j < 4; j++)
        acc[i][j] = __builtin_amdgcn_mfma_f32_16x16x32_bf16(bv[j], af[i], acc[i][j], 0, 0, 0);
    __syncthreads();
  }
  // epilogue: thread (quad,lm) holds rows m0+wr*64+i*16+lm, cols n0+wc*64+j*16+quad*4+r
#pragma unroll
  for (int i = 0; i < 4; i++) {
    int gr = m0 + wr * 64 + i * 16 + lm;
    if (gr < M) {
      bf16* crow = C + (size_t)gr * ldc;
#pragma unroll
      for (int j = 0; j < 4; j++) {
        int gc = n0 + wc * 64 + j * 16 + quad * 4;
        float4 bia = *(const float4*)(bias + gc);
        float v0 = acc[i][j][0] + bia.x;
        float v1 = acc[i][j][1] + bia.y;
        float v2 = acc[i][j][2] + bia.z;
        float v3 = acc[i][j][3] + bia.w;
        if (flags & GEMM_GELU) {
          v0 = gelu_f(v0); v1 = gelu_f(v1); v2 = gelu_f(v2); v3 = gelu_f(v3);
        }
        bf16x4 o = {(bf16)v0, (bf16)v1, (bf16)v2, (bf16)v3};
        *(bf16x4*)(crow + gc) = o;
      }
    }
  }
}

// ---------------- segment sum via CSR (strided rows) ----------------
__global__ __launch_bounds__(256) void segsum_k(
    const int* __restrict__ offs, const int* __restrict__ cols,
    const bf16* __restrict__ in, int ldin, bf16* __restrict__ out, int ldout, int nseg)
{
  int wid = threadIdx.x >> 6, lane = threadIdx.x & 63;
  int seg = blockIdx.x * 4 + wid;
  if (seg >= nseg) return;
  int b = offs[seg], e = offs[seg + 1];
  float a0 = 0.f, a1 = 0.f, a2 = 0.f, a3 = 0.f;
  for (int i = b; i < e; i++) {
    int c = cols[i];
    bf16x4 v = *(const bf16x4*)(in + (size_t)c * ldin + lane * 4);
    a0 += (float)v.x; a1 += (float)v.y; a2 += (float)v.z; a3 += (float)v.w;
  }
  bf16x4 o = {(bf16)a0, (bf16)a1, (bf16)a2, (bf16)a3};
  *(bf16x4*)(out + (size_t)seg * ldout + lane * 4) = o;
}

// ---------------- fused residual + (gelu) + LayerNorm ----------------
__global__ __launch_bounds__(256) void ln_k(
    const bf16* __restrict__ X, int ldx, const bf16* __restrict__ A,
    const float* __restrict__ gam, const float* __restrict__ bet,
    bf16* __restrict__ outb, float* __restrict__ outf, int M, int apply_gelu)
{
  int wid = threadIdx.x >> 6, lane = threadIdx.x & 63;
  int row = blockIdx.x * 4 + wid;
  if (row >= M) return;
  size_t xbase = (size_t)row * ldx + lane * 4;
  size_t abase = (size_t)row * HD + lane * 4;
  bf16x4 xv = *(const bf16x4*)(X + xbase);
  bf16x4 av = *(const bf16x4*)(A + abase);
  float s0, s1, s2, s3;
  if (apply_gelu) {
    s0 = (float)xv.x + gelu_f((float)av.x);
    s1 = (float)xv.y + gelu_f((float)av.y);
    s2 = (float)xv.z + gelu_f((float)av.z);
    s3 = (float)xv.w + gelu_f((float)av.w);
  } else {
    s0 = (float)xv.x + (float)av.x;
    s1 = (float)xv.y + (float)av.y;
    s2 = (float)xv.z + (float)av.z;
    s3 = (float)xv.w + (float)av.w;
  }
  float sum = s0 + s1 + s2 + s3;
#pragma unroll
  for (int o = 32; o; o >>= 1) sum += __shfl_xor(sum, o, 64);
  float mean = sum * (1.0f / 256.0f);
  float d0 = s0 - mean, d1 = s1 - mean, d2 = s2 - mean, d3 = s3 - mean;
  float vs = d0 * d0 + d1 * d1 + d2 * d2 + d3 * d3;
#pragma unroll
  for (int o = 32; o; o >>= 1) vs += __shfl_xor(vs, o, 64);
  float rstd = rsqrtf(vs * (1.0f / 256.0f) + 1e-5f);
  float4 g = *(const float4*)(gam + lane * 4);
  float4 bb = *(const float4*)(bet + lane * 4);
  float y0 = d0 * rstd * g.x + bb.x;
  float y1 = d1 * rstd * g.y + bb.y;
  float y2 = d2 * rstd * g.z + bb.z;
  float y3 = d3 * rstd * g.w + bb.w;
  if (outb) {
    bf16x4 o = {(bf16)y0, (bf16)y1, (bf16)y2, (bf16)y3};
    *(bf16x4*)(outb + xbase) = o;
  }
  if (outf) {
    float4 o = {y0, y1, y2, y3};
    *(float4*)(outf + abase) = o;
  }
}

// ---------------- lg_x init ----------------
__global__ __launch_bounds__(256) void gather_rel_k(
    const int* __restrict__ feat, const float* __restrict__ rel,
    bf16* __restrict__ out, int ldout, int NE)
{
  int wid = threadIdx.x >> 6, lane = threadIdx.x & 63;
  int e = blockIdx.x * 4 + wid;
  if (e >= NE) return;
  int f = feat[e];
  float4 v = *(const float4*)(rel + (size_t)f * HD + lane * 4);
  bf16x4 o = {(bf16)v.x, (bf16)v.y, (bf16)v.z, (bf16)v.w};
  *(bf16x4*)(out + (size_t)e * ldout + lane * 4) = o;
}

// ---------------- fused_edges: out[e] = x[src[e]] + x[dst[e]] ----------------
__global__ __launch_bounds__(256) void gather2_k(
    const int* __restrict__ src, const int* __restrict__ dst,
    const bf16* __restrict__ x, int ldx, bf16* __restrict__ out, int ldout, int NE)
{
  int wid = threadIdx.x >> 6, lane = threadIdx.x & 63;
  int e = blockIdx.x * 4 + wid;
  if (e >= NE) return;
  int s = src[e], d = dst[e];
  bf16x4 a = *(const bf16x4*)(x + (size_t)s * ldx + lane * 4);
  bf16x4 b = *(const bf16x4*)(x + (size_t)d * ldx + lane * 4);
  bf16x4 o = {(bf16)((float)a.x + (float)b.x), (bf16)((float)a.y + (float)b.y),
              (bf16)((float)a.z + (float)b.z), (bf16)((float)a.w + (float)b.w)};
  *(bf16x4*)(out + (size_t)e * ldout + lane * 4) = o;
}

// ---------------- f32 row copy -> bf16 strided ----------------
__global__ __launch_bounds__(256) void f2b_k(const float* __restrict__ in,
                                             bf16* __restrict__ out, int ldout, int M) {
  int wid = threadIdx.x >> 6, lane = threadIdx.x & 63;
  int row = blockIdx.x * 4 + wid;
  if (row >= M) return;
  float4 v = *(const float4*)(in + (size_t)row * HD + lane * 4);
  bf16x4 o = {(bf16)v.x, (bf16)v.y, (bf16)v.z, (bf16)v.w};
  *(bf16x4*)(out + (size_t)row * ldout + lane * 4) = o;
}

// ---------------- weight transpose+convert ----------------
__global__ __launch_bounds__(256) void wtrans_k(const float* __restrict__ in, bf16* __restrict__ out,
                                                int Kd, int Nd) {
  size_t moff = (size_t)blockIdx.y * Kd * Nd;
  int id = blockIdx.x * 256 + threadIdx.x;
  if (id >= Kd * Nd) return;
  int n = id / Kd, k = id - n * Kd;
  out[moff + id] = (bf16)in[moff + (size_t)k * Nd + n];
}

// ---------------- cat weight build ----------------
__global__ __launch_bounds__(256) void wcat_k(const float* __restrict__ ws, const float* __restrict__ wk,
                                              const float* __restrict__ wf, bf16* __restrict__ out,
                                              int KH, int CW) {
  int mi = blockIdx.y;
  int id = blockIdx.x * 256 + threadIdx.x;
  if (id >= HD * CW) return;
  int n = id / CW, k = id - n * CW;
  int s = k >> 8, kk = k & 255;
  float v;
  if (s == 0)       v = ws[((size_t)mi * HD + kk) * HD + n];
  else if (s <= KH) v = wk[(((size_t)mi * KH + (s - 1)) * HD + kk) * HD + n];
  else              v = wf[((size_t)mi * HD + kk) * HD + n];
  out[(size_t)mi * HD * CW + id] = (bf16)v;
}

// ---------------- cat bias ----------------
__global__ __launch_bounds__(256) void bcat_k(const float* __restrict__ bs, const float* __restrict__ bk,
                                              const float* __restrict__ bf, float* __restrict__ out, int KH) {
  int mi = blockIdx.x, n = threadIdx.x;
  float v = bs[(size_t)mi * HD + n] + bf[(size_t)mi * HD + n];
  for (int i = 0; i < KH; i++) v += bk[((size_t)mi * KH + i) * HD + n];
  out[(size_t)mi * HD + n] = v;
}

// ---------------- CSR build ----------------
__global__ __launch_bounds__(256) void count_k(const int* __restrict__ keys, int n, int* __restrict__ cnt) {
  int i = blockIdx.x * 256 + threadIdx.x;
  if (i < n) atomicAdd(&cnt[keys[i]], 1);
}
__global__ __launch_bounds__(256) void scan1_k(const int* __restrict__ in, int* __restrict__ out,
                                               int* __restrict__ bsum, int n) {
  __shared__ int sh[256];
  int t = threadIdx.x;
  int i0 = blockIdx.x * 1024 + t * 4;
  int v0 = (i0 < n) ? in[i0] : 0;
  int v1 = (i0 + 1 < n) ? in[i0 + 1] : 0;
  int v2 = (i0 + 2 < n) ? in[i0 + 2] : 0;
  int v3 = (i0 + 3 < n) ? in[i0 + 3] : 0;
  int tsum = v0 + v1 + v2 + v3;
  sh[t] = tsum;
  __syncthreads();
  for (int o = 1; o < 256; o <<= 1) {
    int x = (t >= o) ? sh[t - o] : 0;
    __syncthreads();
    sh[t] += x;
    __syncthreads();
  }
  int e0 = sh[t] - tsum;
  if (t == 255) bsum[blockIdx.x] = sh[255];
  if (i0 < n) out[i0] = e0;
  e0 += v0;
  if (i0 + 1 < n) out[i0 + 1] = e0;
  e0 += v1;
  if (i0 + 2 < n) out[i0 + 2] = e0;
  e0 += v2;
  if (i0 + 3 < n) out[i0 + 3] = e0;
}
__global__ void scan2_k(int* bsum, int nb, int* total) {
  if (threadIdx.x == 0 && blockIdx.x == 0) {
    int acc = 0;
    for (int i = 0; i < nb; i++) { int v = bsum[i]; bsum[i] = acc; acc += v; }
    *total = acc;
  }
}
__global__ __launch_bounds__(256) void scan3_k(int* out, const int* bsum, int n) {
  int i = blockIdx.x * 256 + threadIdx.x;
  if (i < n) out[i] += bsum[i >> 10];
}
__global__ __launch_bounds__(256) void fill_k(const int* __restrict__ keys, const int* __restrict__ vals,
                                              int n, int modE, int* __restrict__ cursor, int* __restrict__ cols) {
  int i = blockIdx.x * 256 + threadIdx.x;
  if (i >= n) return;
  int pos = atomicAdd(&cursor[keys[i]], 1);
  cols[pos] = vals ? vals[i] : (i < modE ? i : i - modE);
}

extern "C" void kernel_launch(void* const* d_in, const int* in_sizes, int n_in,
                              void* d_out, int out_size, void* d_ws, size_t ws_size,
                              hipStream_t stream)
{
  const float* x_in      = (const float*)d_in[0];
  const int*   edge_feat = (const int*)d_in[1];
  const int*   eig       = (const int*)d_in[2];
  const int*   eil       = (const int*)d_in[3];
  const float* rel       = (const float*)d_in[4];
  const float* w_self = (const float*)d_in[5];
  const float* b_self = (const float*)d_in[6];
  const float* w_khop = (const float*)d_in[7];
  const float* b_khop = (const float*)d_in[8];
  const float* w_fuse = (const float*)d_in[9];
  const float* b_fuse = (const float*)d_in[10];
  const float* w_ff1  = (const float*)d_in[11];
  const float* b_ff1  = (const float*)d_in[12];
  const float* w_ff2  = (const float*)d_in[13];
  const float* b_ff2  = (const float*)d_in[14];
  const float* ln1_g  = (const float*)d_in[15];
  const float* ln1_b  = (const float*)d_in[16];
  const float* ln2_g  = (const float*)d_in[17];
  const float* ln2_b  = (const float*)d_in[18];

  const int NN = in_sizes[0] / HD;
  const int NE = in_sizes[1];
  const int NL = in_sizes[3] / 2;
  const int L  = in_sizes[5] / (2 * HD * HD);
  const int KH = in_sizes[7] / (L * 2 * HD * HD);
  const int CW = (KH + 2) * HD;   // cat width: x | z1..zKH | fused

  char* p = (char*)d_ws;
  auto alloc = [&](size_t bytes) -> void* {
    void* r = (void*)p;
    p += (bytes + 255) & ~(size_t)255;
    return r;
  };

  bf16* n_cat  = (bf16*)alloc((size_t)NN * CW * 2);
  bf16* lg_cat = (bf16*)alloc((size_t)NE * CW * 2);
  bf16* acc_n  = (bf16*)alloc((size_t)NN * HD * 2);
  bf16* acc_e  = (bf16*)alloc((size_t)NE * HD * 2);

  bf16*  wcat_t = (bf16*)alloc((size_t)L * 2 * HD * CW * 2);
  float* bcat   = (float*)alloc((size_t)L * 2 * HD * 4);
  bf16*  wff1_t = (bf16*)alloc((size_t)L * 2 * HD * 4 * HD * 2);
  bf16*  wff2_t = (bf16*)alloc((size_t)L * 2 * HD * 4 * HD * 2);

  int* inc_offs = (int*)alloc((size_t)(NN + 1) * 4);
  int* inc_cur  = (int*)alloc((size_t)NN * 4);
  int* inc_cols = (int*)alloc((size_t)2 * NE * 4);
  int* ng_offs  = (int*)alloc((size_t)(NN + 1) * 4);
  int* ng_cur   = (int*)alloc((size_t)NN * 4);
  int* ng_cols  = (int*)alloc((size_t)NE * 4);
  int* lg_offs  = (int*)alloc((size_t)(NE + 1) * 4);
  int* lg_cur   = (int*)alloc((size_t)NE * 4);
  int* lg_cols  = (int*)alloc((size_t)NL * 4);
  int* bsum     = (int*)alloc(3 * 256 * 4);

  // ---- weights ----
  wcat_k<<<dim3((HD * CW + 255) / 256, L * 2), 256, 0, stream>>>(w_self, w_khop, w_fuse, wcat_t, KH, CW);
  bcat_k<<<L * 2, 256, 0, stream>>>(b_self, b_khop, b_fuse, bcat, KH);
  wtrans_k<<<dim3((HD * 4 * HD + 255) / 256, L * 2), 256, 0, stream>>>(w_ff1, wff1_t, HD, 4 * HD);
  wtrans_k<<<dim3((HD * 4 * HD + 255) / 256, L * 2), 256, 0, stream>>>(w_ff2, wff2_t, 4 * HD, HD);

  // ---- activation init ----
  f2b_k<<<(NN + 3) / 4, 256, 0, stream>>>(x_in, n_cat, CW, NN);
  gather_rel_k<<<(NE + 3) / 4, 256, 0, stream>>>(edge_feat, rel, lg_cat, CW, NE);

  // ---- CSR builds ----
  auto build_csr = [&](const int* keys, int nkeys, const int* vals, int modE,
                       int nseg, int* offs, int* cur, int* cols, int* bs) {
    int nb = (nseg + 1023) / 1024;
    hipMemsetAsync(offs, 0, (size_t)(nseg + 1) * 4, stream);
    count_k<<<(nkeys + 255) / 256, 256, 0, stream>>>(keys, nkeys, offs);
    scan1_k<<<nb, 256, 0, stream>>>(offs, offs, bs, nseg);
    scan2_k<<<1, 1, 0, stream>>>(bs, nb, offs + nseg);
    scan3_k<<<(nseg + 255) / 256, 256, 0, stream>>>(offs, bs, nseg);
    hipMemcpyAsync(cur, offs, (size_t)nseg * 4, hipMemcpyDeviceToDevice, stream);
    fill_k<<<(nkeys + 255) / 256, 256, 0, stream>>>(keys, vals, nkeys, modE, cur, cols);
  };
  build_csr(eig, 2 * NE, nullptr, NE, NN, inc_offs, inc_cur, inc_cols, bsum);
  build_csr(eig + NE, NE, eig, 0, NN, ng_offs, ng_cur, ng_cols, bsum + 256);
  build_csr(eil + NL, NL, eil, 0, NE, lg_offs, lg_cur, lg_cols, bsum + 512);

  float* out_x  = (float*)d_out;
  float* out_lg = (float*)d_out + (size_t)NN * HD;

  auto run_core = [&](bf16* cat, bf16* accb, const int* coffs, const int* ccols,
                      int M, int l, int c, float* outf) {
    size_t mi = (size_t)(l * 2 + c);
    int mb = (M + 127) / 128;
    // khop chain into slices 1..KH
    for (int i = 1; i <= KH; i++)
      segsum_k<<<(M + 3) / 4, 256, 0, stream>>>(coffs, ccols, cat + (size_t)(i - 1) * HD, CW,
                                                cat + (size_t)i * HD, CW, M);
    // acc = cat @ Wcat + bcat   (self + khops + fuse, one K=1536 GEMM)
    gemm_k<<<dim3(2, mb), 256, 0, stream>>>(cat, wcat_t + mi * HD * CW, bcat + mi * HD,
                                            accb, M, CW, CW, HD, 0);
    // t = LN1(x + gelu(acc)) -> slice0
    ln_k<<<(M + 3) / 4, 256, 0, stream>>>(cat, CW, accb, ln1_g + mi * HD, ln1_b + mi * HD,
                                          cat, (float*)nullptr, M, 1);
    // FFN, chunked through a reused scratch region (rows 0..FC of slices 1..4)
    // so the hidden chunk stays LLC-resident instead of round-tripping HBM.
    bf16* hid = cat + HD;                 // scratch: slice1..4, rows [0, FC)
    int FC = (M > 40000) ? 40000 : M;
    for (int c0 = 0; c0 < M; c0 += FC) {
      int mc = (M - c0 < FC) ? (M - c0) : FC;
      int mbc = (mc + 127) / 128;
      gemm_k<<<dim3(8, mbc), 256, 0, stream>>>(cat + (size_t)c0 * CW, wff1_t + mi * HD * 4 * HD,
                                               b_ff1 + mi * 4 * HD, hid, mc, HD, CW, CW, GEMM_GELU);
      gemm_k<<<dim3(2, mbc), 256, 0, stream>>>(hid, wff2_t + mi * 4 * HD * HD, b_ff2 + mi * HD,
                                               accb + (size_t)c0 * HD, mc, 4 * HD, CW, HD, 0);
    }
    // x_new = LN2(t + acc) -> slice0 (+ f32 out on last layer)
    ln_k<<<(M + 3) / 4, 256, 0, stream>>>(cat, CW, accb, ln2_g + mi * HD, ln2_b + mi * HD,
                                          cat, outf, M, 0);
  };

  for (int l = 0; l < L; l++) {
    segsum_k<<<(NN + 3) / 4, 256, 0, stream>>>(inc_offs, inc_cols, lg_cat, CW,
                                               n_cat + (size_t)(KH + 1) * HD, CW, NN);
    gather2_k<<<(NE + 3) / 4, 256, 0, stream>>>(eig, eig + NE, n_cat, CW,
                                                lg_cat + (size_t)(KH + 1) * HD, CW, NE);
    run_core(n_cat, acc_n, ng_offs, ng_cols, NN, l, 0, (l == L - 1) ? out_x : nullptr);
    run_core(lg_cat, acc_e, lg_offs, lg_cols, NE, l, 1, (l == L - 1) ? out_lg : nullptr);
  }
}